// Round 3
// baseline (864.732 us; speedup 1.0000x reference)
//
#include <hip/hip_runtime.h>
#include <math.h>

constexpr int NODES = 100000;
constexpr int F = 64;       // features
constexpr int C = 40;       // classes
constexpr int NPB = 128;    // nodes per bucket
constexpr int BUCKETS = (NODES + NPB - 1) / NPB;   // 782
constexpr int CAP = 4096;   // edge capacity per bucket (avg ~2046, max ~2.3k)
constexpr int CSTRIDE = 16; // cursor padded to 64B line to kill same-line atomic contention

// ---------------------------------------------------------------------------
// Pass A: bin edges into 128-node buckets. pack = src | (dst&127)<<20  (u32)
// ---------------------------------------------------------------------------
__global__ __launch_bounds__(256)
void bucket_scatter(const int* __restrict__ src, const int* __restrict__ dst,
                    int* __restrict__ bcursor, unsigned* __restrict__ bbuf,
                    int nedges) {
    int e = blockIdx.x * 256 + threadIdx.x;
    if (e >= nedges) return;
    int s = src[e];
    int d = dst[e];
    if ((unsigned)s >= (unsigned)NODES || (unsigned)d >= (unsigned)NODES) return;
    int b = d >> 7;
    unsigned pack = (unsigned)s | ((unsigned)(d & 127) << 20);
    int p = atomicAdd(&bcursor[b * CSTRIDE], 1);
    if (p < CAP) bbuf[(size_t)b * CAP + p] = pack;
}

// ---------------------------------------------------------------------------
// Pass B: one block per bucket. Edge phase: wave-per-edge, lane=feature,
// ds_add_f32 into padded LDS acc[128][65] (conflict-free: 65 ≡ 1 mod 32).
// Epilogue: thread-per-node GEMVs with uniform (scalarized) weight loads.
// ---------------------------------------------------------------------------
__global__ __launch_bounds__(256)
void bucket_fused(const float* __restrict__ x,
                  const unsigned* __restrict__ bbuf,
                  const int* __restrict__ bcursor,
                  const float* __restrict__ wl,
                  const float* __restrict__ bl,
                  const float* __restrict__ wr,
                  float* __restrict__ out) {
    __shared__ float acc[NPB * (F + 1)];   // 33.3 KB
    __shared__ int sdeg[NPB];

    int t = threadIdx.x;
    for (int i = t; i < NPB * (F + 1); i += 256) acc[i] = 0.0f;
    if (t < NPB) sdeg[t] = 0;
    __syncthreads();

    int b = blockIdx.x;
    int cnt = bcursor[b * CSTRIDE];
    if (cnt > CAP) cnt = CAP;
    const unsigned* eb = bbuf + (size_t)b * CAP;
    int lane = t & 63;
    int wave = t >> 6;

    // wave w handles edges j = w, w+4, w+8, ... ; 2-deep manual pipeline
    int j = wave;
    for (; j + 8 <= cnt; j += 8) {
        unsigned p0 = eb[j];
        unsigned p1 = eb[j + 4];
        int s0 = p0 & 0xFFFFF, d0 = (int)(p0 >> 20);
        int s1 = p1 & 0xFFFFF, d1 = (int)(p1 >> 20);
        float v0 = x[(size_t)s0 * F + lane];
        float v1 = x[(size_t)s1 * F + lane];
        atomicAdd(&acc[d0 * (F + 1) + lane], v0);
        atomicAdd(&acc[d1 * (F + 1) + lane], v1);
        if (lane == 0) { atomicAdd(&sdeg[d0], 1); atomicAdd(&sdeg[d1], 1); }
    }
    for (; j < cnt; j += 4) {
        unsigned p0 = eb[j];
        int s0 = p0 & 0xFFFFF, d0 = (int)(p0 >> 20);
        float v0 = x[(size_t)s0 * F + lane];
        atomicAdd(&acc[d0 * (F + 1) + lane], v0);
        if (lane == 0) atomicAdd(&sdeg[d0], 1);
    }
    __syncthreads();

    // ---- epilogue: threads 0..127, one node each ----
    if (t >= NPB) return;
    int n = b * NPB + t;
    if (n >= NODES) return;

    float invd = 1.0f / (float)max(sdeg[t], 1);

    float4 o[10];
    const float4* bl4 = (const float4*)bl;   // uniform -> s_load
#pragma unroll
    for (int q = 0; q < 10; ++q) o[q] = bl4[q];

    const float* arow = &acc[t * (F + 1)];
    const float4* xr  = (const float4*)(x + (size_t)n * F);
    const float4* wl4 = (const float4*)wl;   // uniform indices -> s_load_dwordx4
    const float4* wr4 = (const float4*)wr;

    for (int f4 = 0; f4 < F / 4; ++f4) {
        float4 xv = xr[f4];
        float xf[4] = {xv.x, xv.y, xv.z, xv.w};
        float af[4];
#pragma unroll
        for (int jj = 0; jj < 4; ++jj) af[jj] = arow[f4 * 4 + jj] * invd;
#pragma unroll
        for (int jj = 0; jj < 4; ++jj) {
            int f = f4 * 4 + jj;
#pragma unroll
            for (int q = 0; q < 10; ++q) {
                float4 wlv = wl4[f * 10 + q];
                float4 wrv = wr4[f * 10 + q];
                o[q].x = fmaf(af[jj], wlv.x, fmaf(xf[jj], wrv.x, o[q].x));
                o[q].y = fmaf(af[jj], wlv.y, fmaf(xf[jj], wrv.y, o[q].y));
                o[q].z = fmaf(af[jj], wlv.z, fmaf(xf[jj], wrv.z, o[q].z));
                o[q].w = fmaf(af[jj], wlv.w, fmaf(xf[jj], wrv.w, o[q].w));
            }
        }
    }

    float m = -1e30f;
#pragma unroll
    for (int q = 0; q < 10; ++q)
        m = fmaxf(m, fmaxf(fmaxf(o[q].x, o[q].y), fmaxf(o[q].z, o[q].w)));
    float ssum = 0.0f;
#pragma unroll
    for (int q = 0; q < 10; ++q)
        ssum += __expf(o[q].x - m) + __expf(o[q].y - m) +
                __expf(o[q].z - m) + __expf(o[q].w - m);
    float lse = m + __logf(ssum);

    float4* op = (float4*)(out + (size_t)n * C);
#pragma unroll
    for (int q = 0; q < 10; ++q) {
        float4 v;
        v.x = o[q].x - lse;
        v.y = o[q].y - lse;
        v.z = o[q].z - lse;
        v.w = o[q].w - lse;
        op[q] = v;
    }
}

// ===========================================================================
// Fallback (R1 path) if workspace too small
// ===========================================================================
__global__ __launch_bounds__(256)
void scatter_kernel(const float* __restrict__ x,
                    const int* __restrict__ src,
                    const int* __restrict__ dst,
                    float* __restrict__ aggsum,
                    float* __restrict__ deg,
                    int nedges) {
    int lane = threadIdx.x & 63;
    int e = blockIdx.x * 4 + (threadIdx.x >> 6);
    if (e >= nedges) return;
    int s = src[e];
    int d = dst[e];
    if ((unsigned)s >= (unsigned)NODES || (unsigned)d >= (unsigned)NODES) return;
    float v = x[(size_t)s * F + lane];
    atomicAdd(&aggsum[(size_t)d * F + lane], v);
    if (lane == 0) atomicAdd(&deg[d], 1.0f);
}

__global__ __launch_bounds__(256)
void meanify_kernel(float* __restrict__ aggsum, const float* __restrict__ deg) {
    int lane = threadIdx.x & 63;
    int n = blockIdx.x * 4 + (threadIdx.x >> 6);
    if (n >= NODES) return;
    float inv = 1.0f / fmaxf(deg[n], 1.0f);
    aggsum[(size_t)n * F + lane] *= inv;
}

__global__ __launch_bounds__(256)
void node_kernel(const float* __restrict__ x,
                 const float* __restrict__ aggmean,
                 const float* __restrict__ wl,
                 const float* __restrict__ bl,
                 const float* __restrict__ wr,
                 float* __restrict__ out) {
    __shared__ alignas(16) float sWl[F * C];
    __shared__ alignas(16) float sWr[F * C];
    __shared__ alignas(16) float sb[C];
    for (int i = threadIdx.x; i < F * C; i += 256) { sWl[i] = wl[i]; sWr[i] = wr[i]; }
    if (threadIdx.x < C) sb[threadIdx.x] = bl[threadIdx.x];
    __syncthreads();
    int n = blockIdx.x * 256 + threadIdx.x;
    if (n >= NODES) return;
    float4 acc[10];
    const float4* sb4 = (const float4*)sb;
#pragma unroll
    for (int q = 0; q < 10; ++q) acc[q] = sb4[q];
    const float4* xr  = (const float4*)(x       + (size_t)n * F);
    const float4* ar  = (const float4*)(aggmean + (size_t)n * F);
    const float4* wl4 = (const float4*)sWl;
    const float4* wr4 = (const float4*)sWr;
    for (int f4 = 0; f4 < F / 4; ++f4) {
        float4 xv = xr[f4];
        float4 av = ar[f4];
        float xs[4]  = {xv.x, xv.y, xv.z, xv.w};
        float as_[4] = {av.x, av.y, av.z, av.w};
#pragma unroll
        for (int jj = 0; jj < 4; ++jj) {
            int f = f4 * 4 + jj;
#pragma unroll
            for (int q = 0; q < 10; ++q) {
                float4 wlv = wl4[f * 10 + q];
                float4 wrv = wr4[f * 10 + q];
                acc[q].x = fmaf(as_[jj], wlv.x, fmaf(xs[jj], wrv.x, acc[q].x));
                acc[q].y = fmaf(as_[jj], wlv.y, fmaf(xs[jj], wrv.y, acc[q].y));
                acc[q].z = fmaf(as_[jj], wlv.z, fmaf(xs[jj], wrv.z, acc[q].z));
                acc[q].w = fmaf(as_[jj], wlv.w, fmaf(xs[jj], wrv.w, acc[q].w));
            }
        }
    }
    float m = -1e30f;
#pragma unroll
    for (int q = 0; q < 10; ++q)
        m = fmaxf(m, fmaxf(fmaxf(acc[q].x, acc[q].y), fmaxf(acc[q].z, acc[q].w)));
    float ssum = 0.0f;
#pragma unroll
    for (int q = 0; q < 10; ++q)
        ssum += __expf(acc[q].x - m) + __expf(acc[q].y - m) +
                __expf(acc[q].z - m) + __expf(acc[q].w - m);
    float lse = m + __logf(ssum);
    float4* op = (float4*)(out + (size_t)n * C);
#pragma unroll
    for (int q = 0; q < 10; ++q) {
        float4 v;
        v.x = acc[q].x - lse; v.y = acc[q].y - lse;
        v.z = acc[q].z - lse; v.w = acc[q].w - lse;
        op[q] = v;
    }
}

extern "C" void kernel_launch(void* const* d_in, const int* in_sizes, int n_in,
                              void* d_out, int out_size, void* d_ws, size_t ws_size,
                              hipStream_t stream) {
    const float* x     = (const float*)d_in[0];
    const int*   index = (const int*)d_in[1];
    const float* wl    = (const float*)d_in[2];
    const float* bl    = (const float*)d_in[3];
    const float* wr    = (const float*)d_in[4];
    float* out = (float*)d_out;

    int nedges = in_sizes[1] / 2;
    const int* src = index;
    const int* dst = index + nedges;

    // --- bucket workspace layout ---
    // [bcursor: BUCKETS*CSTRIDE ints (64B-padded)][bbuf: BUCKETS*CAP u32]
    size_t need = (size_t)BUCKETS * CSTRIDE * 4 + (size_t)BUCKETS * CAP * 4;

    if (ws_size >= need) {
        int* bcursor  = (int*)d_ws;
        unsigned* bbuf = (unsigned*)(bcursor + (size_t)BUCKETS * CSTRIDE);

        hipMemsetAsync(bcursor, 0, (size_t)BUCKETS * CSTRIDE * 4, stream);

        int eblk = (nedges + 255) / 256;
        bucket_scatter<<<eblk, 256, 0, stream>>>(src, dst, bcursor, bbuf, nedges);
        bucket_fused<<<BUCKETS, 256, 0, stream>>>(x, bbuf, bcursor, wl, bl, wr, out);
    } else {
        float* aggsum = (float*)d_ws;
        float* deg    = aggsum + (size_t)NODES * F;
        size_t zbytes = ((size_t)NODES * F + (size_t)NODES) * sizeof(float);
        hipMemsetAsync(d_ws, 0, zbytes, stream);

        int nblk4 = (nedges + 3) / 4;
        scatter_kernel<<<nblk4, 256, 0, stream>>>(x, src, dst, aggsum, deg, nedges);
        meanify_kernel<<<(NODES + 3) / 4, 256, 0, stream>>>(aggsum, deg);
        node_kernel<<<(NODES + 255) / 256, 256, 0, stream>>>(
            x, aggsum, wl, bl, wr, out);
    }
}

// Round 4
// 401.158 us; speedup vs baseline: 2.1556x; 2.1556x over previous
//
#include <hip/hip_runtime.h>
#include <math.h>

constexpr int NODES = 100000;
constexpr int F = 64;      // features
constexpr int C = 40;      // classes

__device__ inline void f4add(float4& a, const float4 b) {
    a.x += b.x; a.y += b.y; a.z += b.z; a.w += b.w;
}
__device__ inline float4 f4shfl_xor(float4 v, int m) {
    float4 r;
    r.x = __shfl_xor(v.x, m);
    r.y = __shfl_xor(v.y, m);
    r.z = __shfl_xor(v.z, m);
    r.w = __shfl_xor(v.w, m);
    return r;
}

// ===========================================================================
// CSR pipeline: hist -> ticket offsets -> bin(nt-store) -> aggregate_v2
// ===========================================================================

__global__ __launch_bounds__(256)
void hist_kernel(const int* __restrict__ src, const int* __restrict__ dst,
                 int* __restrict__ degi, int nedges) {
    int e = blockIdx.x * 256 + threadIdx.x;
    if (e >= nedges) return;
    int s = src[e];
    int d = dst[e];
    if ((unsigned)s >= (unsigned)NODES || (unsigned)d >= (unsigned)NODES) return;
    atomicAdd(&degi[d], 1);
}

__global__ __launch_bounds__(256)
void offsets_kernel(const int* __restrict__ degi, int* __restrict__ gcount,
                    int* __restrict__ off, int* __restrict__ cursor) {
    int n = blockIdx.x * 256 + threadIdx.x;
    if (n >= NODES) return;
    int d = degi[n];
    int o = atomicAdd(gcount, d);   // disjoint regions; order irrelevant
    off[n] = o;
    cursor[n] = o;
}

__global__ __launch_bounds__(256)
void bin_kernel(const int* __restrict__ src, const int* __restrict__ dst,
                int* __restrict__ cursor, int* __restrict__ sorted_src, int nedges) {
    int e = blockIdx.x * 256 + threadIdx.x;
    if (e >= nedges) return;
    int s = src[e];
    int d = dst[e];
    if ((unsigned)s >= (unsigned)NODES || (unsigned)d >= (unsigned)NODES) return;
    int p = atomicAdd(&cursor[d], 1);
    // nontemporal: no L2 allocate -> no full-line dirty-evict per 4B store
    __builtin_nontemporal_store(s, &sorted_src[p]);
}

// One wave per node. lane = (edge-group g = lane>>4) x (float4 slot q = lane&15).
// Each iteration gathers 4..16 full 256B rows via dwordx4; cross-group shfl
// reduce at the end; 16-lane float4 coalesced row store.
__global__ __launch_bounds__(256)
void aggregate_v2(const float* __restrict__ x,
                  const int* __restrict__ sorted_src,
                  const int* __restrict__ off,
                  const int* __restrict__ degi,
                  float* __restrict__ aggmean) {
    int t = threadIdx.x;
    int lane = t & 63;
    int n = blockIdx.x * 4 + (t >> 6);
    if (n >= NODES) return;
    int base = off[n];
    int cnt  = degi[n];
    int g = lane >> 4;
    int q = lane & 15;

    const float4* x4 = (const float4*)x;
    float4 a0 = make_float4(0.f, 0.f, 0.f, 0.f);
    float4 a1 = a0, a2 = a0, a3 = a0;

    int j = 0;
    for (; j + 16 <= cnt; j += 16) {           // 16 rows in flight per wave
        int s0 = sorted_src[base + j +      g];
        int s1 = sorted_src[base + j +  4 + g];
        int s2 = sorted_src[base + j +  8 + g];
        int s3 = sorted_src[base + j + 12 + g];
        float4 v0 = x4[(size_t)s0 * 16 + q];
        float4 v1 = x4[(size_t)s1 * 16 + q];
        float4 v2 = x4[(size_t)s2 * 16 + q];
        float4 v3 = x4[(size_t)s3 * 16 + q];
        f4add(a0, v0); f4add(a1, v1); f4add(a2, v2); f4add(a3, v3);
    }
    for (; j < cnt; j += 4) {                  // masked tail, 4 rows/iter
        int e = j + g;
        if (e < cnt) {
            int s = sorted_src[base + e];
            float4 v = x4[(size_t)s * 16 + q];
            f4add(a0, v);
        }
    }
    f4add(a0, a1); f4add(a2, a3); f4add(a0, a2);
    f4add(a0, f4shfl_xor(a0, 16));
    f4add(a0, f4shfl_xor(a0, 32));

    if (g == 0) {
        float inv = 1.0f / (float)max(cnt, 1);
        float4 r;
        r.x = a0.x * inv; r.y = a0.y * inv; r.z = a0.z * inv; r.w = a0.w * inv;
        ((float4*)aggmean)[(size_t)n * 16 + q] = r;
    }
}

// ===========================================================================
// Phase 2: out = aggmean @ Wl + b + x @ Wr, then log_softmax. Thread/node.
// ===========================================================================
__global__ __launch_bounds__(256)
void node_kernel(const float* __restrict__ x,
                 const float* __restrict__ aggmean,
                 const float* __restrict__ wl,
                 const float* __restrict__ bl,
                 const float* __restrict__ wr,
                 float* __restrict__ out) {
    __shared__ alignas(16) float sWl[F * C];
    __shared__ alignas(16) float sWr[F * C];
    __shared__ alignas(16) float sb[C];
    for (int i = threadIdx.x; i < F * C; i += 256) { sWl[i] = wl[i]; sWr[i] = wr[i]; }
    if (threadIdx.x < C) sb[threadIdx.x] = bl[threadIdx.x];
    __syncthreads();

    int n = blockIdx.x * 256 + threadIdx.x;
    if (n >= NODES) return;

    float4 acc[10];
    const float4* sb4 = (const float4*)sb;
#pragma unroll
    for (int q = 0; q < 10; ++q) acc[q] = sb4[q];

    const float4* xr  = (const float4*)(x       + (size_t)n * F);
    const float4* ar  = (const float4*)(aggmean + (size_t)n * F);
    const float4* wl4 = (const float4*)sWl;
    const float4* wr4 = (const float4*)sWr;

    for (int f4 = 0; f4 < F / 4; ++f4) {
        float4 xv = xr[f4];
        float4 av = ar[f4];
        float xs[4]  = {xv.x, xv.y, xv.z, xv.w};
        float as_[4] = {av.x, av.y, av.z, av.w};
#pragma unroll
        for (int jj = 0; jj < 4; ++jj) {
            int f = f4 * 4 + jj;
#pragma unroll
            for (int q = 0; q < 10; ++q) {
                float4 wlv = wl4[f * 10 + q];
                float4 wrv = wr4[f * 10 + q];
                acc[q].x = fmaf(as_[jj], wlv.x, fmaf(xs[jj], wrv.x, acc[q].x));
                acc[q].y = fmaf(as_[jj], wlv.y, fmaf(xs[jj], wrv.y, acc[q].y));
                acc[q].z = fmaf(as_[jj], wlv.z, fmaf(xs[jj], wrv.z, acc[q].z));
                acc[q].w = fmaf(as_[jj], wlv.w, fmaf(xs[jj], wrv.w, acc[q].w));
            }
        }
    }

    float m = -1e30f;
#pragma unroll
    for (int q = 0; q < 10; ++q)
        m = fmaxf(m, fmaxf(fmaxf(acc[q].x, acc[q].y), fmaxf(acc[q].z, acc[q].w)));
    float ssum = 0.0f;
#pragma unroll
    for (int q = 0; q < 10; ++q)
        ssum += __expf(acc[q].x - m) + __expf(acc[q].y - m) +
                __expf(acc[q].z - m) + __expf(acc[q].w - m);
    float lse = m + __logf(ssum);

    float4* op = (float4*)(out + (size_t)n * C);
#pragma unroll
    for (int q = 0; q < 10; ++q) {
        float4 v;
        v.x = acc[q].x - lse; v.y = acc[q].y - lse;
        v.z = acc[q].z - lse; v.w = acc[q].w - lse;
        op[q] = v;
    }
}

// ===========================================================================
// Fallback (atomic scatter) if workspace too small
// ===========================================================================
__global__ __launch_bounds__(256)
void scatter_kernel(const float* __restrict__ x,
                    const int* __restrict__ src,
                    const int* __restrict__ dst,
                    float* __restrict__ aggsum,
                    float* __restrict__ deg,
                    int nedges) {
    int lane = threadIdx.x & 63;
    int e = blockIdx.x * 4 + (threadIdx.x >> 6);
    if (e >= nedges) return;
    int s = src[e];
    int d = dst[e];
    if ((unsigned)s >= (unsigned)NODES || (unsigned)d >= (unsigned)NODES) return;
    float v = x[(size_t)s * F + lane];
    atomicAdd(&aggsum[(size_t)d * F + lane], v);
    if (lane == 0) atomicAdd(&deg[d], 1.0f);
}

__global__ __launch_bounds__(256)
void meanify_kernel(float* __restrict__ aggsum, const float* __restrict__ deg) {
    int lane = threadIdx.x & 63;
    int n = blockIdx.x * 4 + (threadIdx.x >> 6);
    if (n >= NODES) return;
    float inv = 1.0f / fmaxf(deg[n], 1.0f);
    aggsum[(size_t)n * F + lane] *= inv;
}

extern "C" void kernel_launch(void* const* d_in, const int* in_sizes, int n_in,
                              void* d_out, int out_size, void* d_ws, size_t ws_size,
                              hipStream_t stream) {
    const float* x     = (const float*)d_in[0];
    const int*   index = (const int*)d_in[1];
    const float* wl    = (const float*)d_in[2];
    const float* bl    = (const float*)d_in[3];
    const float* wr    = (const float*)d_in[4];
    float* out = (float*)d_out;

    int nedges = in_sizes[1] / 2;
    const int* src = index;
    const int* dst = index + nedges;

    // ws layout: [degi N][gcount 1][off N][cursor N][sorted_src E][aggmean N*F]
    size_t need = (size_t)(3 * NODES + 1) * 4 + (size_t)nedges * 4
                + (size_t)NODES * F * 4;

    if (ws_size >= need) {
        int* degi       = (int*)d_ws;
        int* gcount     = degi + NODES;
        int* off        = gcount + 1;
        int* cursor     = off + NODES;
        int* sorted_src = cursor + NODES;
        float* aggmean  = (float*)(sorted_src + nedges);

        hipMemsetAsync(degi, 0, (size_t)(NODES + 1) * sizeof(int), stream);

        int eblk = (nedges + 255) / 256;
        int nblk = (NODES + 255) / 256;
        hist_kernel<<<eblk, 256, 0, stream>>>(src, dst, degi, nedges);
        offsets_kernel<<<nblk, 256, 0, stream>>>(degi, gcount, off, cursor);
        bin_kernel<<<eblk, 256, 0, stream>>>(src, dst, cursor, sorted_src, nedges);
        aggregate_v2<<<(NODES + 3) / 4, 256, 0, stream>>>(
            x, sorted_src, off, degi, aggmean);
        node_kernel<<<nblk, 256, 0, stream>>>(x, aggmean, wl, bl, wr, out);
    } else {
        float* aggsum = (float*)d_ws;
        float* deg    = aggsum + (size_t)NODES * F;
        size_t zbytes = ((size_t)NODES * F + (size_t)NODES) * sizeof(float);
        hipMemsetAsync(d_ws, 0, zbytes, stream);

        int nblk4 = (nedges + 3) / 4;
        scatter_kernel<<<nblk4, 256, 0, stream>>>(x, src, dst, aggsum, deg, nedges);
        meanify_kernel<<<(NODES + 3) / 4, 256, 0, stream>>>(aggsum, deg);
        node_kernel<<<(NODES + 255) / 256, 256, 0, stream>>>(
            x, aggsum, wl, bl, wr, out);
    }
}